// Round 1
// baseline (1566.151 us; speedup 1.0000x reference)
//
#include <hip/hip_runtime.h>
#include <hip/hip_bf16.h>

// Problem config (static):
// B=2, N=6, D=48, FH=16, FW=44, C=80 ; out = [B, C, 1, 256, 256]
// Nprime = 405504 points, each scatter-adds its 80-channel feature vector
// into voxel (b, gy, gx) of a 256x256 BEV grid (NZ=1).
//
// Numerical contract: reference ('np') assumed float64 with f32-*valued*
// constants (frustum built from np.float32 ops; LOWER/DX declared jnp.float32).
// Geometry here is double precision seeded with bit-exact f32 frustum values.

#define NPTS      405504
#define PTS_PER_BN 33792   // D*FH*FW = 48*16*44
#define HW_       704      // FH*FW... no: FW*? -> r/704 gives d ; 16*44=704
#define FWIDTH    44
#define NCH       80
#define GRID_HW   65536    // 256*256
#define OUT_PER_B 5242880  // 80*65536

__device__ inline void inv3(const double a[9], double inv[9]) {
    double c00 =  a[4]*a[8] - a[5]*a[7];
    double c01 = -(a[3]*a[8] - a[5]*a[6]);
    double c02 =  a[3]*a[7] - a[4]*a[6];
    double det = a[0]*c00 + a[1]*c01 + a[2]*c02;
    double id  = 1.0/det;
    inv[0] = c00*id;
    inv[1] = (a[2]*a[7]-a[1]*a[8])*id;
    inv[2] = (a[1]*a[5]-a[2]*a[4])*id;
    inv[3] = c01*id;
    inv[4] = (a[0]*a[8]-a[2]*a[6])*id;
    inv[5] = (a[2]*a[3]-a[0]*a[5])*id;
    inv[6] = c02*id;
    inv[7] = (a[1]*a[6]-a[0]*a[7])*id;
    inv[8] = (a[0]*a[4]-a[1]*a[3])*id;
}

// Per-(b,n): ws[bn*24 + 0..8] = inv(post_rots), [9..17] = rots @ inv(intrins),
//            [18..20] = post_trans, [21..23] = trans   (all double)
__global__ void prep_kernel(const float* __restrict__ rots,
                            const float* __restrict__ trans,
                            const float* __restrict__ intrins,
                            const float* __restrict__ post_rots,
                            const float* __restrict__ post_trans,
                            double* __restrict__ ws) {
    int bn = threadIdx.x;
    if (bn >= 12) return;
    double pr[9], kk[9], rt[9], ipr[9], ik[9];
    #pragma unroll
    for (int i = 0; i < 9; i++) {
        pr[i] = (double)post_rots[bn*9 + i];
        kk[i] = (double)intrins[bn*9 + i];
        rt[i] = (double)rots[bn*9 + i];
    }
    inv3(pr, ipr);
    inv3(kk, ik);
    double* o = ws + bn*24;
    #pragma unroll
    for (int i = 0; i < 9; i++) o[i] = ipr[i];
    #pragma unroll
    for (int r = 0; r < 3; r++)
        #pragma unroll
        for (int c = 0; c < 3; c++)
            o[9 + r*3 + c] = rt[r*3+0]*ik[0*3+c] + rt[r*3+1]*ik[1*3+c] + rt[r*3+2]*ik[2*3+c];
    #pragma unroll
    for (int i = 0; i < 3; i++) o[18 + i] = (double)post_trans[bn*3 + i];
    #pragma unroll
    for (int i = 0; i < 3; i++) o[21 + i] = (double)trans[bn*3 + i];
}

__global__ __launch_bounds__(256) void scatter_kernel(const float* __restrict__ x,
                                                      const double* __restrict__ ws,
                                                      float* __restrict__ out) {
    __shared__ int s_base[256];
    const int tid = threadIdx.x;
    const int blockStart = blockIdx.x * 256;      // 1584 blocks * 256 = 405504 exactly
    const int p = blockStart + tid;

    // ---- phase 1: geometry for this thread's point ----
    const int bn = p / PTS_PER_BN;                // camera id in [0,12)
    const int r  = p - bn * PTS_PER_BN;
    const int d  = r / HW_;
    const int r2 = r - d * HW_;
    const int h  = r2 / FWIDTH;
    const int w  = r2 - h * FWIDTH;
    const int b  = bn / 6;

    // frustum values, bit-exact float32 per numpy:
    //   xs = np.linspace(0,703,44,dtype=f32): f64 compute (w * 703/43), cast f32, endpoint pinned
    //   ys = np.linspace(0,255,16,dtype=f32): exact h*17
    //   ds = f32(2.0) + f32(56/48) * f32(d)  (separate f32 mul then add, no FMA)
    float xs  = (w == 43) ? 703.0f : (float)((double)w * (703.0 / 43.0));
    float ysv = (float)(h * 17);
    float dsv = __fadd_rn(2.0f, __fmul_rn((float)(56.0 / 48.0), (float)d));

    const double* t = ws + bn * 24;
    double px = (double)xs  - t[18];
    double py = (double)ysv - t[19];
    double pz = (double)dsv - t[20];
    // inv(post_rots) @ p
    double q0 = t[0]*px + t[1]*py + t[2]*pz;
    double q1 = t[3]*px + t[4]*py + t[5]*pz;
    double q2 = t[6]*px + t[7]*py + t[8]*pz;
    // un-normalize by depth
    q0 *= q2;
    q1 *= q2;
    // combine @ p + trans
    double e0 = t[9]*q0  + t[10]*q1 + t[11]*q2 + t[21];
    double e1 = t[12]*q0 + t[13]*q1 + t[14]*q2 + t[22];
    double e2 = t[15]*q0 + t[16]*q1 + t[17]*q2 + t[23];

    // voxelize: (g - LOWER)/DX with f32-valued constants, truncation toward zero
    const double lxy = (double)(-51.2f);
    const double dxy = (double)(0.4f);
    const double lz  = (double)(-10.0f);
    const double dz  = (double)(20.0f);
    int gx = (int)((e0 - lxy) / dxy);
    int gy = (int)((e1 - lxy) / dxy);
    int gz = (int)((e2 - lz) / dz);

    int base = -1;
    if (gx >= 0 && gx < 256 && gy >= 0 && gy < 256 && gz == 0)
        base = b * OUT_PER_B + gy * 256 + gx;
    s_base[tid] = base;
    __syncthreads();

    // ---- phase 2: coalesced feature reads + scatter atomics ----
    // 256 points * 80 ch = 5120 float4 chunks = 20 per thread
    const float4* xv = (const float4*)(x + (size_t)blockStart * NCH);
    #pragma unroll 4
    for (int it = 0; it < 20; it++) {
        int chunk = it * 256 + tid;
        int pl = chunk / 20;          // local point
        int c4 = chunk - pl * 20;     // channel quad
        float4 v = xv[chunk];
        int bse = s_base[pl];
        if (bse >= 0) {
            float* o = out + bse + c4 * 4 * GRID_HW;
            atomicAdd(o,                v.x);
            atomicAdd(o + GRID_HW,      v.y);
            atomicAdd(o + 2 * GRID_HW,  v.z);
            atomicAdd(o + 3 * GRID_HW,  v.w);
        }
    }
}

extern "C" void kernel_launch(void* const* d_in, const int* in_sizes, int n_in,
                              void* d_out, int out_size, void* d_ws, size_t ws_size,
                              hipStream_t stream) {
    const float* x          = (const float*)d_in[0];
    const float* rots       = (const float*)d_in[1];
    const float* trans      = (const float*)d_in[2];
    const float* intrins    = (const float*)d_in[3];
    const float* post_rots  = (const float*)d_in[4];
    const float* post_trans = (const float*)d_in[5];
    float*  out = (float*)d_out;
    double* ws  = (double*)d_ws;

    // out is poisoned 0xAA before every timed call — zero it.
    hipMemsetAsync(d_out, 0, (size_t)out_size * sizeof(float), stream);
    prep_kernel<<<1, 64, 0, stream>>>(rots, trans, intrins, post_rots, post_trans, ws);
    scatter_kernel<<<NPTS / 256, 256, 0, stream>>>(x, ws, out);
}

// Round 2
// 337.798 us; speedup vs baseline: 4.6364x; 4.6364x over previous
//
#include <hip/hip_runtime.h>
#include <hip/hip_bf16.h>

// LSS voxel pooling: B=2,N=6,D=48,FH=16,FW=44,C=80 -> out [2,80,1,256,256]
// R1 analysis: atomic-serialization bound (WRITE_SIZE 890MB for 42MB out; the
// h-dimension and cameras collapse onto the same BEV voxel -> ~96-way
// same-address contention). R2: LDS privatization — block = (bn, d, w-tile)
// covering all 16 h, hash-aggregate <=16 unique voxels in LDS, flush once.
//
// Numerics (verified R1, absmax 0.125): f64 geometry seeded with bit-exact
// f32 frustum values + f32-valued bounds constants; trunc-toward-zero voxelize.

#define NPTS      405504
#define PTS_PER_BN 33792   // D*FH*FW
#define NCH       80
#define GRID_HW   65536    // 256*256
#define OUT_PER_B 5242880  // 80*65536
#define NSLOT     32

__device__ inline void inv3(const double a[9], double inv[9]) {
    double c00 =  a[4]*a[8] - a[5]*a[7];
    double c01 = -(a[3]*a[8] - a[5]*a[6]);
    double c02 =  a[3]*a[7] - a[4]*a[6];
    double det = a[0]*c00 + a[1]*c01 + a[2]*c02;
    double id  = 1.0/det;
    inv[0] = c00*id;
    inv[1] = (a[2]*a[7]-a[1]*a[8])*id;
    inv[2] = (a[1]*a[5]-a[2]*a[4])*id;
    inv[3] = c01*id;
    inv[4] = (a[0]*a[8]-a[2]*a[6])*id;
    inv[5] = (a[2]*a[3]-a[0]*a[5])*id;
    inv[6] = c02*id;
    inv[7] = (a[1]*a[6]-a[0]*a[7])*id;
    inv[8] = (a[0]*a[4]-a[1]*a[3])*id;
}

// ws[bn*24 + 0..8]=inv(post_rots), [9..17]=rots@inv(intrins),
// [18..20]=post_trans, [21..23]=trans (double)
__global__ void prep_kernel(const float* __restrict__ rots,
                            const float* __restrict__ trans,
                            const float* __restrict__ intrins,
                            const float* __restrict__ post_rots,
                            const float* __restrict__ post_trans,
                            double* __restrict__ ws) {
    int bn = threadIdx.x;
    if (bn >= 12) return;
    double pr[9], kk[9], rt[9], ipr[9], ik[9];
    #pragma unroll
    for (int i = 0; i < 9; i++) {
        pr[i] = (double)post_rots[bn*9 + i];
        kk[i] = (double)intrins[bn*9 + i];
        rt[i] = (double)rots[bn*9 + i];
    }
    inv3(pr, ipr);
    inv3(kk, ik);
    double* o = ws + bn*24;
    #pragma unroll
    for (int i = 0; i < 9; i++) o[i] = ipr[i];
    #pragma unroll
    for (int r = 0; r < 3; r++)
        #pragma unroll
        for (int c = 0; c < 3; c++)
            o[9 + r*3 + c] = rt[r*3+0]*ik[0*3+c] + rt[r*3+1]*ik[1*3+c] + rt[r*3+2]*ik[2*3+c];
    #pragma unroll
    for (int i = 0; i < 3; i++) o[18 + i] = (double)post_trans[bn*3 + i];
    #pragma unroll
    for (int i = 0; i < 3; i++) o[21 + i] = (double)trans[bn*3 + i];
}

// Block = (bn, d, wtile): 16 h x 16 w = 256 points, all h-collapse in-block.
// Grid = 12 * 48 * 3 = 1728 blocks.
__global__ __launch_bounds__(256) void scatter_kernel(const float* __restrict__ x,
                                                      const double* __restrict__ ws,
                                                      float* __restrict__ out) {
    __shared__ int   s_key[NSLOT];
    __shared__ float s_acc[NSLOT][NCH];     // 10 KB
    __shared__ int   s_slot[256];
    __shared__ int   s_base[256];

    const int tid = threadIdx.x;
    const int bid = blockIdx.x;
    const int bn  = bid / 144;              // 48*3
    const int rem = bid - bn * 144;
    const int d   = rem / 3;
    const int wt  = rem - d * 3;
    const int w0  = wt * 16;
    const int h   = tid >> 4;
    const int wl  = tid & 15;
    const int w   = w0 + wl;
    const int b   = bn / 6;
    const bool valid = (w < 44);

    // init LDS
    if (tid < NSLOT) s_key[tid] = -1;
    {
        float* sa = &s_acc[0][0];
        #pragma unroll
        for (int i = 0; i < (NSLOT * NCH) / 256; i++) sa[i * 256 + tid] = 0.0f;
    }

    // ---- geometry (f64, f32-seeded; verified numerics from R1) ----
    int base = -1;
    if (valid) {
        float xsv = (w == 43) ? 703.0f : (float)((double)w * (703.0 / 43.0));
        float ysv = (float)(h * 17);
        float dsv = __fadd_rn(2.0f, __fmul_rn((float)(56.0 / 48.0), (float)d));

        const double* t = ws + bn * 24;
        double px = (double)xsv - t[18];
        double py = (double)ysv - t[19];
        double pz = (double)dsv - t[20];
        double q0 = t[0]*px + t[1]*py + t[2]*pz;
        double q1 = t[3]*px + t[4]*py + t[5]*pz;
        double q2 = t[6]*px + t[7]*py + t[8]*pz;
        q0 *= q2;
        q1 *= q2;
        double e0 = t[9]*q0  + t[10]*q1 + t[11]*q2 + t[21];
        double e1 = t[12]*q0 + t[13]*q1 + t[14]*q2 + t[22];
        double e2 = t[15]*q0 + t[16]*q1 + t[17]*q2 + t[23];

        const double lxy = (double)(-51.2f);
        const double dxy = (double)(0.4f);
        const double lz  = (double)(-10.0f);
        const double dz  = (double)(20.0f);
        int gx = (int)((e0 - lxy) / dxy);
        int gy = (int)((e1 - lxy) / dxy);
        int gz = (int)((e2 - lz) / dz);
        if (gx >= 0 && gx < 256 && gy >= 0 && gy < 256 && gz == 0)
            base = b * OUT_PER_B + gy * 256 + gx;
    }
    s_base[tid] = base;
    __syncthreads();

    // ---- hash insert: base -> slot (expect <=16 unique; 32 slots + fallback) ----
    int slot = -1;
    if (base >= 0) {
        int hh = (base ^ (base >> 5)) & (NSLOT - 1);
        for (int probe = 0; probe < NSLOT; probe++) {
            int sidx = (hh + probe) & (NSLOT - 1);
            int prev = atomicCAS(&s_key[sidx], -1, base);
            if (prev == -1 || prev == base) { slot = sidx; break; }
        }
    }
    s_slot[tid] = slot;
    __syncthreads();

    // ---- phase 2: coalesced x loads, LDS accumulation ----
    // 256 points * 20 float4-chunks; chunk -> (local point, channel quad)
    for (int it = 0; it < 20; it++) {
        int chunk = it * 256 + tid;
        int pl = chunk / 20;
        int c4 = chunk - pl * 20;
        int pb = s_base[pl];
        if (pb >= 0) {
            int ph  = pl >> 4;
            int pw  = w0 + (pl & 15);
            size_t off = ((size_t)bn * PTS_PER_BN + d * 704 + ph * 44 + pw) * NCH + c4 * 4;
            const float4 v = *(const float4*)(x + off);
            int sl = s_slot[pl];
            if (sl >= 0) {
                atomicAdd(&s_acc[sl][c4*4 + 0], v.x);
                atomicAdd(&s_acc[sl][c4*4 + 1], v.y);
                atomicAdd(&s_acc[sl][c4*4 + 2], v.z);
                atomicAdd(&s_acc[sl][c4*4 + 3], v.w);
            } else {                      // hash-full fallback (shouldn't trigger)
                float* o = out + pb + (size_t)(c4*4) * GRID_HW;
                atomicAdd(o,              v.x);
                atomicAdd(o + GRID_HW,    v.y);
                atomicAdd(o + 2*GRID_HW,  v.z);
                atomicAdd(o + 3*GRID_HW,  v.w);
            }
        }
    }
    __syncthreads();

    // ---- phase 3: flush unique voxels (<=32*80 = 2560 atomics/block) ----
    #pragma unroll
    for (int it = 0; it < (NSLOT * NCH) / 256; it++) {
        int idx = it * 256 + tid;
        int sl  = idx / NCH;
        int c   = idx - sl * NCH;
        int k   = s_key[sl];
        if (k >= 0)
            atomicAdd(out + (size_t)k + (size_t)c * GRID_HW, s_acc[sl][c]);
    }
}

extern "C" void kernel_launch(void* const* d_in, const int* in_sizes, int n_in,
                              void* d_out, int out_size, void* d_ws, size_t ws_size,
                              hipStream_t stream) {
    const float* x          = (const float*)d_in[0];
    const float* rots       = (const float*)d_in[1];
    const float* trans      = (const float*)d_in[2];
    const float* intrins    = (const float*)d_in[3];
    const float* post_rots  = (const float*)d_in[4];
    const float* post_trans = (const float*)d_in[5];
    float*  out = (float*)d_out;
    double* ws  = (double*)d_ws;

    hipMemsetAsync(d_out, 0, (size_t)out_size * sizeof(float), stream);
    prep_kernel<<<1, 64, 0, stream>>>(rots, trans, intrins, post_rots, post_trans, ws);
    scatter_kernel<<<12 * 48 * 3, 256, 0, stream>>>(x, ws, out);
}

// Round 3
// 282.104 us; speedup vs baseline: 5.5517x; 1.1974x over previous
//
#include <hip/hip_runtime.h>
#include <hip/hip_bf16.h>

// LSS voxel pooling: B=2,N=6,D=48,FH=16,FW=44,C=80 -> out [2,80,1,256,256]
// R2 analysis: LDS-atomic serialization bound (35M LDS atomics, ~12-way
// same-address within wave). R3: exploit geometry structure — gx=f(d),
// gy=f(w,d), only keptness (gz) depends on h. Reduce the 16-h dimension in
// REGISTERS per (w-column, channel-quad), flush one float4 of global atomics
// per column-quad (2.0M total, spread). Per-h fallback path keeps generality.
// Custom zero_kernel replaces hipMemsetAsync (R2 had ~160us outside scatter).
//
// Numerics (verified R1/R2, absmax 0.03): f64 geometry seeded with bit-exact
// f32 frustum values + f32-valued bounds constants; trunc-toward-zero.

#define PTS_PER_BN 33792   // D*FH*FW = 48*16*44
#define NCH       80
#define GRID_HW   65536    // 256*256
#define OUT_PER_B 5242880  // 80*65536
#define HSTRIDE   3520     // 44*80 floats between h rows

__device__ inline void inv3(const double a[9], double inv[9]) {
    double c00 =  a[4]*a[8] - a[5]*a[7];
    double c01 = -(a[3]*a[8] - a[5]*a[6]);
    double c02 =  a[3]*a[7] - a[4]*a[6];
    double det = a[0]*c00 + a[1]*c01 + a[2]*c02;
    double id  = 1.0/det;
    inv[0] = c00*id;
    inv[1] = (a[2]*a[7]-a[1]*a[8])*id;
    inv[2] = (a[1]*a[5]-a[2]*a[4])*id;
    inv[3] = c01*id;
    inv[4] = (a[0]*a[8]-a[2]*a[6])*id;
    inv[5] = (a[2]*a[3]-a[0]*a[5])*id;
    inv[6] = c02*id;
    inv[7] = (a[1]*a[6]-a[0]*a[7])*id;
    inv[8] = (a[0]*a[4]-a[1]*a[3])*id;
}

// ws[bn*24 + 0..8]=inv(post_rots), [9..17]=rots@inv(intrins),
// [18..20]=post_trans, [21..23]=trans (double)
__global__ void prep_kernel(const float* __restrict__ rots,
                            const float* __restrict__ trans,
                            const float* __restrict__ intrins,
                            const float* __restrict__ post_rots,
                            const float* __restrict__ post_trans,
                            double* __restrict__ ws) {
    int bn = threadIdx.x;
    if (bn >= 12) return;
    double pr[9], kk[9], rt[9], ipr[9], ik[9];
    #pragma unroll
    for (int i = 0; i < 9; i++) {
        pr[i] = (double)post_rots[bn*9 + i];
        kk[i] = (double)intrins[bn*9 + i];
        rt[i] = (double)rots[bn*9 + i];
    }
    inv3(pr, ipr);
    inv3(kk, ik);
    double* o = ws + bn*24;
    #pragma unroll
    for (int i = 0; i < 9; i++) o[i] = ipr[i];
    #pragma unroll
    for (int r = 0; r < 3; r++)
        #pragma unroll
        for (int c = 0; c < 3; c++)
            o[9 + r*3 + c] = rt[r*3+0]*ik[0*3+c] + rt[r*3+1]*ik[1*3+c] + rt[r*3+2]*ik[2*3+c];
    #pragma unroll
    for (int i = 0; i < 3; i++) o[18 + i] = (double)post_trans[bn*3 + i];
    #pragma unroll
    for (int i = 0; i < 3; i++) o[21 + i] = (double)trans[bn*3 + i];
}

__global__ __launch_bounds__(256) void zero_kernel(float4* __restrict__ out, int n4) {
    int i = blockIdx.x * 256 + threadIdx.x;
    int stride = gridDim.x * 256;
    for (; i < n4; i += stride) out[i] = make_float4(0.f, 0.f, 0.f, 0.f);
}

// Block = (bn, d): all 16h x 44w of one depth slice. Grid = 12*48 = 576.
__global__ __launch_bounds__(256) void scatter_kernel(const float* __restrict__ x,
                                                      const double* __restrict__ ws,
                                                      float* __restrict__ out) {
    __shared__ int s_base[704];     // per (h,w) voxel base or -1
    __shared__ int s_colbase[44];   // per w: base of first kept h (or -1)
    __shared__ unsigned s_mask[44]; // per w: h-bits where base == colbase
    __shared__ unsigned s_fb[44];   // per w: h-bits where base != colbase (general-input fallback)

    const int tid = threadIdx.x;
    const int bid = blockIdx.x;
    const int bn  = bid / 48;
    const int d   = bid - bn * 48;
    const int b   = bn / 6;

    const double* t = ws + bn * 24;
    const float dsv = __fadd_rn(2.0f, __fmul_rn((float)(56.0 / 48.0), (float)d));

    // ---- phase 1: per-point geometry -> s_base ----
    for (int idx = tid; idx < 704; idx += 256) {
        const int h = idx / 44;
        const int w = idx - h * 44;
        float xsv = (w == 43) ? 703.0f : (float)((double)w * (703.0 / 43.0));
        float ysv = (float)(h * 17);

        double px = (double)xsv - t[18];
        double py = (double)ysv - t[19];
        double pz = (double)dsv - t[20];
        double q0 = t[0]*px + t[1]*py + t[2]*pz;
        double q1 = t[3]*px + t[4]*py + t[5]*pz;
        double q2 = t[6]*px + t[7]*py + t[8]*pz;
        q0 *= q2;
        q1 *= q2;
        double e0 = t[9]*q0  + t[10]*q1 + t[11]*q2 + t[21];
        double e1 = t[12]*q0 + t[13]*q1 + t[14]*q2 + t[22];
        double e2 = t[15]*q0 + t[16]*q1 + t[17]*q2 + t[23];

        const double lxy = (double)(-51.2f);
        const double dxy = (double)(0.4f);
        int gx = (int)((e0 - lxy) / dxy);
        int gy = (int)((e1 - lxy) / dxy);
        int gz = (int)((e2 - (double)(-10.0f)) / (double)(20.0f));
        int base = -1;
        if (gx >= 0 && gx < 256 && gy >= 0 && gy < 256 && gz == 0)
            base = b * OUT_PER_B + gy * 256 + gx;
        s_base[idx] = base;
    }
    __syncthreads();

    // ---- phase 1b: per-column base + masks ----
    if (tid < 44) {
        int cb = -1; unsigned mm = 0, fb = 0;
        #pragma unroll
        for (int h = 0; h < 16; h++) {
            int pb = s_base[h * 44 + tid];
            if (pb >= 0) {
                if (cb < 0) cb = pb;
                if (pb == cb) mm |= (1u << h);
                else          fb |= (1u << h);
            }
        }
        s_colbase[tid] = cb;
        s_mask[tid]    = mm;
        s_fb[tid]      = fb;
    }
    __syncthreads();

    // ---- phase 2: register h-reduction per (w, c4), then one float4 flush ----
    // 44 columns * 20 channel-quads = 880 items; 4 passes of 256 threads.
    const float* xb0 = x + ((size_t)bn * PTS_PER_BN + (size_t)d * 704) * NCH;
    #pragma unroll
    for (int pass = 0; pass < 4; pass++) {
        int item = pass * 256 + tid;
        if (item >= 880) break;
        int w  = item / 20;
        int c4 = item - w * 20;
        unsigned mm = s_mask[w];
        unsigned fb = s_fb[w];
        if (!(mm | fb)) continue;
        const float* xb = xb0 + (size_t)w * NCH + c4 * 4;
        float ax = 0.f, ay = 0.f, az = 0.f, aw = 0.f;
        #pragma unroll
        for (int h = 0; h < 16; h++) {
            if ((mm >> h) & 1u) {
                float4 v = *(const float4*)(xb + h * HSTRIDE);
                ax += v.x; ay += v.y; az += v.z; aw += v.w;
            } else if ((fb >> h) & 1u) {   // general-input path (unused for bench inputs)
                float4 v = *(const float4*)(xb + h * HSTRIDE);
                int pb = s_base[h * 44 + w];
                atomicAdd(out + pb + (size_t)(c4*4 + 0) * GRID_HW, v.x);
                atomicAdd(out + pb + (size_t)(c4*4 + 1) * GRID_HW, v.y);
                atomicAdd(out + pb + (size_t)(c4*4 + 2) * GRID_HW, v.z);
                atomicAdd(out + pb + (size_t)(c4*4 + 3) * GRID_HW, v.w);
            }
        }
        if (mm) {
            int cb = s_colbase[w];
            atomicAdd(out + cb + (size_t)(c4*4 + 0) * GRID_HW, ax);
            atomicAdd(out + cb + (size_t)(c4*4 + 1) * GRID_HW, ay);
            atomicAdd(out + cb + (size_t)(c4*4 + 2) * GRID_HW, az);
            atomicAdd(out + cb + (size_t)(c4*4 + 3) * GRID_HW, aw);
        }
    }
}

extern "C" void kernel_launch(void* const* d_in, const int* in_sizes, int n_in,
                              void* d_out, int out_size, void* d_ws, size_t ws_size,
                              hipStream_t stream) {
    const float* x          = (const float*)d_in[0];
    const float* rots       = (const float*)d_in[1];
    const float* trans      = (const float*)d_in[2];
    const float* intrins    = (const float*)d_in[3];
    const float* post_rots  = (const float*)d_in[4];
    const float* post_trans = (const float*)d_in[5];
    float*  out = (float*)d_out;
    double* ws  = (double*)d_ws;

    zero_kernel<<<2560, 256, 0, stream>>>((float4*)out, out_size / 4);
    prep_kernel<<<1, 64, 0, stream>>>(rots, trans, intrins, post_rots, post_trans, ws);
    scatter_kernel<<<12 * 48, 256, 0, stream>>>(x, ws, out);
}